// Round 2
// baseline (287.318 us; speedup 1.0000x reference)
//
#include <hip/hip_runtime.h>
#include <cstdint>

// Problem constants: view1 (B=8, C=4, H=256, W=256) fp32, F 3x3 fp32.
constexpr int Hh = 256, Ww = 256, BCc = 32;   // BC = B*C = 32 channels
constexpr int CH_PER = 8;                      // channels per thread
constexpr int USPLIT = 2;                      // u-range halves per (pixel,part)

// ---------------------------------------------------------------------------
// Transpose (B,C,H,W) -> T[r][u][ch] via LDS so both sides are coalesced.
// Block: 256 threads handle 128 pixels x 32 ch (16.5 KB LDS, padded stride).
// ---------------------------------------------------------------------------
__global__ __launch_bounds__(256) void fume_transpose(const float* __restrict__ in,
                                                      float* __restrict__ T) {
    __shared__ float lds[BCc][129];            // +1 pad: conflict-free both phases
    const int t = threadIdx.x;
    const int pix0 = blockIdx.x * 128;

#pragma unroll
    for (int j = 0; j < 16; ++j) {             // load: coalesced per channel plane
        int o = j * 256 + t;                   // 0..4095
        int ch = o >> 7;                       // 0..31
        int p  = o & 127;                      // 0..127
        lds[ch][p] = in[ch * (Hh * Ww) + pix0 + p];
    }
    __syncthreads();
#pragma unroll
    for (int j = 0; j < 16; ++j) {             // store: coalesced in T
        int o = j * 256 + t;
        int p  = o >> 5;                       // 0..127
        int ch = o & 31;
        T[(size_t)(pix0 + p) * BCc + ch] = lds[ch][p];
    }
}

// ---------------------------------------------------------------------------
// Main: lane pair = one (pixel, 8-channel part); pair members take low/high
// half of the clipped u-range, combine with shfl_xor. 8192 waves total.
// ---------------------------------------------------------------------------
template <bool USE_T>
__global__ __launch_bounds__(256) void fume_main(const float* __restrict__ src,
                                                 const float* __restrict__ Fm,
                                                 float* __restrict__ out) {
    int g = blockIdx.x * 256 + threadIdx.x;    // 0 .. 65536*4*2-1
    int uhalf = g & (USPLIT - 1);
    int part  = (g >> 1) & 3;
    int pix   = g >> 3;
    int x = pix & (Ww - 1);
    int y = pix >> 8;
    int ch0 = part * CH_PER;

    // Epipolar line l1 = F^T x2, normalized (reference op order).
    float xf = (float)x, yf = (float)y;
    float a = Fm[0] * xf + Fm[3] * yf + Fm[6];
    float b = Fm[1] * xf + Fm[4] * yf + Fm[7];
    float c = Fm[2] * xf + Fm[5] * yf + Fm[8];
    float n = sqrtf(a * a + b * b) + 1e-12f;
    a /= n; b /= n; c /= n;

    float acc[CH_PER];
#pragma unroll
    for (int k = 0; k < CH_PER; ++k) acc[k] = 0.f;

    int u_lo = 0, u_hi = -1;                   // empty unless ok
    float alpha = 0.f, beta = 0.f;
    if (fabsf(b) > 1e-6f) {                    // 'ok' mask
        alpha = -a / b;                        // v(u) = alpha*u + beta
        beta  = -c / b;
        u_hi = Ww - 1;
        // Analytic clip: contribution is exactly 0 unless v in (-1, 256).
        if (fabsf(alpha) > 1e-12f) {
            float t0 = (-1.f  - beta) / alpha;
            float t1 = (256.f - beta) / alpha;
            float tlo = fminf(t0, t1), thi = fmaxf(t0, t1);
            int lo = (int)floorf(tlo);         // cvt clamps on overflow
            int hi = (int)ceilf(thi);
            u_lo = lo > 0 ? lo : 0;
            u_hi = hi < (Ww - 1) ? hi : (Ww - 1);
        } else if (beta <= -1.f || beta >= 256.f) {
            u_hi = -1;
        }
    }

    // Split [u_lo, u_hi] between the lane pair.
    int len = u_hi - u_lo + 1;                 // may be <= 0 (empty)
    int mid = u_lo + (len >> 1);
    int us = uhalf ? mid : u_lo;
    int ue = uhalf ? u_hi : mid - 1;

    for (int u = us; u <= ue; ++u) {
        float v  = fmaf(alpha, (float)u, beta);
        float rf = floorf(v);
        float f  = v - rf;
        int   ri = (int)rf;
        float w0 = ((unsigned)ri       < (unsigned)Hh) ? (1.f - f) : 0.f; // m0
        float w1 = ((unsigned)(ri + 1) < (unsigned)Hh) ? f         : 0.f; // m1
        int r0 = ri < 0 ? 0 : (ri > Hh - 1 ? Hh - 1 : ri);
        int r1 = ri + 1 < 0 ? 0 : (ri + 1 > Hh - 1 ? Hh - 1 : ri + 1);
        if (USE_T) {
            const float4* __restrict__ p0 = reinterpret_cast<const float4*>(
                src + (size_t)(r0 * Ww + u) * BCc + ch0);
            const float4* __restrict__ p1 = reinterpret_cast<const float4*>(
                src + (size_t)(r1 * Ww + u) * BCc + ch0);
            float4 s0a = p0[0], s0b = p0[1];
            float4 s1a = p1[0], s1b = p1[1];
            acc[0] = fmaf(w0, s0a.x, fmaf(w1, s1a.x, acc[0]));
            acc[1] = fmaf(w0, s0a.y, fmaf(w1, s1a.y, acc[1]));
            acc[2] = fmaf(w0, s0a.z, fmaf(w1, s1a.z, acc[2]));
            acc[3] = fmaf(w0, s0a.w, fmaf(w1, s1a.w, acc[3]));
            acc[4] = fmaf(w0, s0b.x, fmaf(w1, s1b.x, acc[4]));
            acc[5] = fmaf(w0, s0b.y, fmaf(w1, s1b.y, acc[5]));
            acc[6] = fmaf(w0, s0b.z, fmaf(w1, s1b.z, acc[6]));
            acc[7] = fmaf(w0, s0b.w, fmaf(w1, s1b.w, acc[7]));
        } else {
#pragma unroll
            for (int k = 0; k < CH_PER; ++k) {
                float s0 = src[(size_t)(ch0 + k) * (Hh * Ww) + r0 * Ww + u];
                float s1 = src[(size_t)(ch0 + k) * (Hh * Ww) + r1 * Ww + u];
                acc[k] = fmaf(w0, s0, fmaf(w1, s1, acc[k]));
            }
        }
    }

    // Combine the two u-halves (lane pair), then half the lanes store.
#pragma unroll
    for (int k = 0; k < CH_PER; ++k)
        acc[k] += __shfl_xor(acc[k], 1, 64);

    if (uhalf == 0) {
#pragma unroll
        for (int k = 0; k < CH_PER; ++k)
            out[(size_t)(ch0 + k) * (Hh * Ww) + pix] = acc[k];
    }
}

extern "C" void kernel_launch(void* const* d_in, const int* in_sizes, int n_in,
                              void* d_out, int out_size, void* d_ws, size_t ws_size,
                              hipStream_t stream) {
    const float* view1 = (const float*)d_in[0];   // 8*4*256*256 fp32
    const float* Fm    = (const float*)d_in[1];   // 9 fp32, row-major 3x3
    float* out = (float*)d_out;

    constexpr size_t t_bytes = (size_t)Hh * Ww * BCc * sizeof(float);  // 8 MiB
    constexpr int n_threads = Hh * Ww * (BCc / CH_PER) * USPLIT;       // 524288
    if (ws_size >= t_bytes) {
        float* T = (float*)d_ws;
        fume_transpose<<<(Hh * Ww) / 128, 256, 0, stream>>>(view1, T);
        fume_main<true><<<n_threads / 256, 256, 0, stream>>>(T, Fm, out);
    } else {
        fume_main<false><<<n_threads / 256, 256, 0, stream>>>(view1, Fm, out);
    }
}

// Round 3
// 141.913 us; speedup vs baseline: 2.0246x; 2.0246x over previous
//
#include <hip/hip_runtime.h>
#include <hip/hip_fp16.h>
#include <cstdint>

// Problem constants: view1 (B=8, C=4, H=256, W=256) fp32, F 3x3 fp32.
constexpr int Hh = 256, Ww = 256, BCc = 32;     // BC = B*C = 32 channels

typedef _Float16 half8 __attribute__((ext_vector_type(8)));

// ---------------------------------------------------------------------------
// Transpose+convert (B,C,H,W) f32 -> T[pix][ch] fp16 (pix = r*256+u).
// Block: 256 threads handle 256 pixels x 32 ch via LDS (both sides coalesced).
// ---------------------------------------------------------------------------
__global__ __launch_bounds__(256) void fume_transpose(const float* __restrict__ in,
                                                      _Float16* __restrict__ T) {
    __shared__ _Float16 lds[256][34];            // stride 34 halves = 68 B: 4B-aligned
    const int t = threadIdx.x;                   // rows, conflict-free both phases
    const int pix0 = blockIdx.x * 256;
#pragma unroll
    for (int ch = 0; ch < BCc; ++ch)             // coalesced per channel plane
        lds[t][ch] = (_Float16)in[ch * (Hh * Ww) + pix0 + t];
    __syncthreads();
    uint32_t* dst = (uint32_t*)(T + (size_t)pix0 * BCc);   // half-pairs
#pragma unroll
    for (int j = 0; j < 16; ++j) {               // coalesced 4B stores
        int o = j * 256 + t;                     // half-pair index in block
        int px = o >> 4;
        int cp = o & 15;
        uint32_t v;
        __builtin_memcpy(&v, &lds[px][2 * cp], 4);
        dst[o] = v;
    }
}

// ---------------------------------------------------------------------------
// Main: thread = (8x8 pixel-tile pixel, 8-channel part). Interior u-steps run
// a mask-free hot loop; boundary steps run the fully-masked edge body.
// ---------------------------------------------------------------------------
template <bool USE_T>
__global__ __launch_bounds__(256) void fume_main(const void* __restrict__ srcv,
                                                 const float* __restrict__ Fm,
                                                 float* __restrict__ out) {
    const int t    = threadIdx.x;
    const int part = t & 3;
    const int px   = t >> 2;                         // 0..63 within 8x8 tile
    const int x    = ((int)blockIdx.x & 31) * 8 + (px & 7);
    const int y    = ((int)blockIdx.x >> 5) * 8 + (px >> 3);
    const int pix  = y * Ww + x;
    const int ch0  = part * 8;

    // Epipolar line l1 = F^T x2, normalized (reference op order).
    float xf = (float)x, yf = (float)y;
    float a = Fm[0] * xf + Fm[3] * yf + Fm[6];
    float b = Fm[1] * xf + Fm[4] * yf + Fm[7];
    float c = Fm[2] * xf + Fm[5] * yf + Fm[8];
    float n = sqrtf(a * a + b * b) + 1e-12f;
    a /= n; b /= n; c /= n;

    float acc[8];
#pragma unroll
    for (int k = 0; k < 8; ++k) acc[k] = 0.f;

    int u_lo = 0, u_hi = -1, i_lo = 0, i_hi = -1;
    float alpha = 0.f, beta = 0.f;
    if (fabsf(b) > 1e-6f) {                          // 'ok' mask
        alpha = -a / b;                              // v(u) = alpha*u + beta
        beta  = -c / b;
        u_lo = 0; u_hi = Ww - 1;
        if (fabsf(alpha) > 1e-12f) {
            float inv = 1.f / alpha;
            // outer clip: contribution exactly 0 unless v in (-1, 256)
            float t0 = (-1.f  - beta) * inv, t1 = (256.f - beta) * inv;
            int lo = (int)floorf(fminf(t0, t1));     // cvt saturates on overflow
            int hi = (int)ceilf (fmaxf(t0, t1));
            u_lo = lo > 0 ? lo : 0;
            u_hi = hi < (Ww - 1) ? hi : (Ww - 1);
            // interior: v in [0, 255) -> both rows valid, no masks
            float s0 = (0.f   - beta) * inv, s1 = (255.f - beta) * inv;
            i_lo = (int)ceilf (fminf(s0, s1));
            i_hi = (int)floorf(fmaxf(s0, s1));
            i_lo = i_lo > u_lo ? i_lo : u_lo;
            i_hi = i_hi < u_hi ? i_hi : u_hi;
        } else {
            if (beta <= -1.f || beta >= 256.f) { u_hi = -1; }
            i_lo = u_lo; i_hi = u_hi;
            if (!(beta >= 0.f && beta < 255.f)) { i_lo = 0; i_hi = -1; }
        }
        // verify-adjust interior endpoints with the exact hot-loop predicate
        // (v monotone in u, so the valid set is an interval)
        while (i_lo <= i_hi) {
            float vv = fmaf(alpha, (float)i_lo, beta);
            if (vv >= 0.f && vv < 255.f) break;
            ++i_lo;
        }
        while (i_lo <= i_hi) {
            float vv = fmaf(alpha, (float)i_hi, beta);
            if (vv >= 0.f && vv < 255.f) break;
            --i_hi;
        }
        if (i_lo > i_hi) { i_lo = u_hi + 1; i_hi = u_hi; }  // no interior
    }
    if (!USE_T) { i_lo = u_hi + 1; i_hi = u_hi; }           // fallback: all masked

    const char*  baseT = (const char*)srcv + part * 16;     // fp16 T + ch0*2
    const float* srcF  = (const float*)srcv;                // fallback layout

    auto edge = [&](int u) {
        float v  = fmaf(alpha, (float)u, beta);
        float rf = floorf(v);
        float f  = v - rf;
        int   ri = (int)rf;
        float w0 = ((unsigned)ri       < (unsigned)Hh) ? (1.f - f) : 0.f;
        float w1 = ((unsigned)(ri + 1) < (unsigned)Hh) ? f         : 0.f;
        int r0 = ri < 0 ? 0 : (ri > Hh - 1 ? Hh - 1 : ri);
        int r1 = ri + 1 < 0 ? 0 : (ri + 1 > Hh - 1 ? Hh - 1 : ri + 1);
        if constexpr (USE_T) {
            half8 s0 = *(const half8*)(baseT + (((r0 << 8) + u) << 6));
            half8 s1 = *(const half8*)(baseT + (((r1 << 8) + u) << 6));
#pragma unroll
            for (int k = 0; k < 8; ++k)
                acc[k] = fmaf((float)s0[k], w0, fmaf((float)s1[k], w1, acc[k]));
        } else {
#pragma unroll
            for (int k = 0; k < 8; ++k) {
                float s0 = srcF[(size_t)(ch0 + k) * (Hh * Ww) + r0 * Ww + u];
                float s1 = srcF[(size_t)(ch0 + k) * (Hh * Ww) + r1 * Ww + u];
                acc[k] = fmaf(w0, s0, fmaf(w1, s1, acc[k]));
            }
        }
    };

    for (int u = u_lo; u < i_lo; ++u) edge(u);              // prologue (masked)

    if constexpr (USE_T) {
#pragma unroll 4
        for (int u = i_lo; u <= i_hi; ++u) {                // hot: mask-free
            float v  = fmaf(alpha, (float)u, beta);
            float rf = floorf(v);
            float f  = v - rf;
            int   ri = (int)rf;                             // in [0,254]
            int  off = ((ri << 8) + u) << 6;
            half8 s0 = *(const half8*)(baseT + off);
            half8 s1 = *(const half8*)(baseT + off + (Ww << 6));
            float w0 = 1.f - f;
#pragma unroll
            for (int k = 0; k < 8; ++k)
                acc[k] = fmaf((float)s1[k], f, fmaf((float)s0[k], w0, acc[k]));
        }
    }

    for (int u = i_hi + 1; u <= u_hi; ++u) edge(u);         // epilogue (masked)

#pragma unroll
    for (int k = 0; k < 8; ++k)
        out[(size_t)(ch0 + k) * (Hh * Ww) + pix] = acc[k];
}

extern "C" void kernel_launch(void* const* d_in, const int* in_sizes, int n_in,
                              void* d_out, int out_size, void* d_ws, size_t ws_size,
                              hipStream_t stream) {
    const float* view1 = (const float*)d_in[0];   // 8*4*256*256 fp32
    const float* Fm    = (const float*)d_in[1];   // 9 fp32, row-major 3x3
    float* out = (float*)d_out;

    constexpr size_t t_bytes = (size_t)Hh * Ww * BCc * sizeof(_Float16);  // 4 MiB
    if (ws_size >= t_bytes) {
        _Float16* T = (_Float16*)d_ws;
        fume_transpose<<<(Hh * Ww) / 256, 256, 0, stream>>>(view1, T);
        fume_main<true><<<(Hh * Ww) / 64, 256, 0, stream>>>(T, Fm, out);
    } else {
        fume_main<false><<<(Hh * Ww) / 64, 256, 0, stream>>>(view1, Fm, out);
    }
}

// Round 4
// 136.207 us; speedup vs baseline: 2.1094x; 1.0419x over previous
//
#include <hip/hip_runtime.h>
#include <cstdint>

// Problem constants: view1 (B=8, C=4, H=256, W=256) fp32, F 3x3 fp32.
constexpr int Hh = 256, Ww = 256, BCc = 32;   // BC = B*C = 32 channels

typedef _Float16 half2v __attribute__((ext_vector_type(2)));
typedef uint32_t uint4v __attribute__((ext_vector_type(4)));

static __device__ inline float fdot2acc(half2v a, half2v b, float c) {
#if __has_builtin(__builtin_amdgcn_fdot2)
    return __builtin_amdgcn_fdot2(a, b, c, false);
#else
    return fmaf((float)a.x, (float)b.x, fmaf((float)a.y, (float)b.y, c));
#endif
}

// ---------------------------------------------------------------------------
// Pack view1 (ch,H,W) f32 -> Tpair[r][u][ch][rr] fp16, rr in {0,1} = rows r,
// r+1 (row 256 zero-padded). One block per r; LDS-staged so stores are linear.
// Word index in Tp: (r*256+u)*32 + ch  (each word = half2 (row r, row r+1)).
// ---------------------------------------------------------------------------
__global__ __launch_bounds__(256) void fume_pack(const float* __restrict__ in,
                                                 uint32_t* __restrict__ Tp) {
    __shared__ uint32_t lds[256 * 33];          // [u][ch], stride 33: 2-way max
    const int u = threadIdx.x;
    const int r = blockIdx.x;
    const bool has1 = (r < Hh - 1);
#pragma unroll
    for (int ch = 0; ch < BCc; ++ch) {          // coalesced per channel plane
        float a = in[ch * (Hh * Ww) + r * Ww + u];
        float b = has1 ? in[ch * (Hh * Ww) + (r + 1) * Ww + u] : 0.f;
        half2v p; p.x = (_Float16)a; p.y = (_Float16)b;
        uint32_t w; __builtin_memcpy(&w, &p, 4);
        lds[u * 33 + ch] = w;
    }
    __syncthreads();
    uint32_t* dst = Tp + (size_t)r * (Ww * BCc);
#pragma unroll
    for (int j = 0; j < 32; ++j) {              // linear coalesced stores
        int o = j * 256 + threadIdx.x;          // 0..8191
        int uu = o >> 5, ch = o & 31;
        dst[o] = lds[uu * 33 + ch];
    }
}

// ---------------------------------------------------------------------------
// Main. Wave = 16 consecutive-x pixels x 4 channel-parts (dv/dx <= 0.19 so
// the wave's samples collapse onto ~2-4 distinct 128B cells per u-step).
// Block = 4 waves at consecutive y (dv/dy ~ 1 -> r-adjacent cells).
// ---------------------------------------------------------------------------
template <bool USE_T>
__global__ __launch_bounds__(256) void fume_main(const void* __restrict__ srcv,
                                                 const float* __restrict__ Fm,
                                                 float* __restrict__ out) {
    const int lane = threadIdx.x & 63;
    const int wv   = threadIdx.x >> 6;
    const int part = lane & 3;                   // channel part: ch0 = part*8
    const int pxx  = lane >> 2;                  // 0..15 within x-strip
    const int x = ((int)blockIdx.x & 15) * 16 + pxx;
    const int y = ((int)blockIdx.x >> 4) * 4 + wv;
    const int pix = y * Ww + x;
    const int ch0 = part * 8;

    // Epipolar line l1 = F^T x2, normalized (reference op order).
    float xf = (float)x, yf = (float)y;
    float a = Fm[0] * xf + Fm[3] * yf + Fm[6];
    float b = Fm[1] * xf + Fm[4] * yf + Fm[7];
    float c = Fm[2] * xf + Fm[5] * yf + Fm[8];
    float n = sqrtf(a * a + b * b) + 1e-12f;
    a /= n; b /= n; c /= n;

    float acc[8];
#pragma unroll
    for (int k = 0; k < 8; ++k) acc[k] = 0.f;

    int u_lo = 0, u_hi = -1;
    float alpha = 0.f, beta = 0.f;
    if (fabsf(b) > 1e-6f) {                      // 'ok' mask
        alpha = -a / b;                          // v(u) = alpha*u + beta
        beta  = -c / b;
        u_lo = 0; u_hi = Ww - 1;
        // Outer clip: contribution exactly 0 unless v in (-1, 256); per-step
        // masks below make boundary rounding harmless.
        if (fabsf(alpha) > 1e-12f) {
            float inv = 1.f / alpha;
            float t0 = (-1.f  - beta) * inv, t1 = (256.f - beta) * inv;
            int lo = (int)floorf(fminf(t0, t1)); // cvt saturates on overflow
            int hi = (int)ceilf (fmaxf(t0, t1));
            u_lo = lo > 0 ? lo : 0;
            u_hi = hi < (Ww - 1) ? hi : (Ww - 1);
        } else if (beta <= -1.f || beta >= 256.f) {
            u_hi = -1;
        }
    }

    if constexpr (USE_T) {
        const uint32_t* base = (const uint32_t*)srcv + part * 8;
#pragma unroll 2
        for (int u = u_lo; u <= u_hi; ++u) {
            float v  = fmaf(alpha, (float)u, beta);
            float rf = floorf(v);
            float f  = v - rf;
            int   ri = (int)rf;
            int   rb = ri < 0 ? 0 : (ri > Hh - 1 ? Hh - 1 : ri);
            bool inb = ((unsigned)ri < (unsigned)Hh);
            // Pair weights vs cell (rb): rows (rb, rb+1). ri==-1 -> f*row0;
            // ri==255 works because Tpair[255][..][1] is zero-padded.
            float w0 = inb ? (1.f - f) : (ri == -1 ? f : 0.f);
            float w1 = inb ? f : 0.f;
            half2v wp; wp.x = (_Float16)w0; wp.y = (_Float16)w1;
            const uint32_t* cell = base + ((((rb << 8) + u)) << 5);
            uint4v c0 = *(const uint4v*)(cell);
            uint4v c1 = *(const uint4v*)(cell + 4);
#pragma unroll
            for (int k = 0; k < 8; ++k) {
                uint32_t w = (k < 4) ? c0[k] : c1[k - 4];
                half2v s; __builtin_memcpy(&s, &w, 4);
                acc[k] = fdot2acc(wp, s, acc[k]);
            }
        }
    } else {
        const float* srcF = (const float*)srcv;
        for (int u = u_lo; u <= u_hi; ++u) {
            float v  = fmaf(alpha, (float)u, beta);
            float rf = floorf(v);
            float f  = v - rf;
            int   ri = (int)rf;
            float w0 = ((unsigned)ri       < (unsigned)Hh) ? (1.f - f) : 0.f;
            float w1 = ((unsigned)(ri + 1) < (unsigned)Hh) ? f         : 0.f;
            int r0 = ri < 0 ? 0 : (ri > Hh - 1 ? Hh - 1 : ri);
            int r1 = ri + 1 < 0 ? 0 : (ri + 1 > Hh - 1 ? Hh - 1 : ri + 1);
#pragma unroll
            for (int k = 0; k < 8; ++k) {
                float s0 = srcF[(size_t)(ch0 + k) * (Hh * Ww) + r0 * Ww + u];
                float s1 = srcF[(size_t)(ch0 + k) * (Hh * Ww) + r1 * Ww + u];
                acc[k] = fmaf(w0, s0, fmaf(w1, s1, acc[k]));
            }
        }
    }

#pragma unroll
    for (int k = 0; k < 8; ++k)
        out[(size_t)(ch0 + k) * (Hh * Ww) + pix] = acc[k];
}

extern "C" void kernel_launch(void* const* d_in, const int* in_sizes, int n_in,
                              void* d_out, int out_size, void* d_ws, size_t ws_size,
                              hipStream_t stream) {
    const float* view1 = (const float*)d_in[0];   // 8*4*256*256 fp32
    const float* Fm    = (const float*)d_in[1];   // 9 fp32, row-major 3x3
    float* out = (float*)d_out;

    constexpr size_t t_bytes = (size_t)Hh * Ww * BCc * 2 * sizeof(_Float16);  // 8 MiB
    if (ws_size >= t_bytes) {
        uint32_t* Tp = (uint32_t*)d_ws;
        fume_pack<<<Hh, 256, 0, stream>>>(view1, Tp);
        fume_main<true><<<(Hh * Ww) / 64, 256, 0, stream>>>(Tp, Fm, out);
    } else {
        fume_main<false><<<(Hh * Ww) / 64, 256, 0, stream>>>(view1, Fm, out);
    }
}